// Round 11
// baseline (446.709 us; speedup 1.0000x reference)
//
#include <hip/hip_runtime.h>
#include <stdint.h>

typedef __attribute__((ext_vector_type(16))) float f32x16;
typedef __attribute__((ext_vector_type(8))) short s16x8;

#define WAITVM(n) asm volatile("s_waitcnt vmcnt(" #n ")" ::: "memory")
#define WAITLGKM0 asm volatile("s_waitcnt lgkmcnt(0)" ::: "memory")

__device__ inline short bf16b(float f) {
  uint32_t x = __float_as_uint(f);
  return (short)((x + 0x7fffu + ((x >> 16) & 1u)) >> 16);  // RNE, finite inputs
}
__device__ inline float bfu(uint16_t u) { return __uint_as_float(((uint32_t)u) << 16); }

__device__ inline void gll16(const void* g, void* l) {
  __builtin_amdgcn_global_load_lds((const __attribute__((address_space(1))) void*)g,
                                   (__attribute__((address_space(3))) void*)l, 16, 0, 0);
}

// ---------------- weight pack: (co,ci,3,3) f32 -> 32x32x16 B-fragment order ----------------
// frag idx = ((tap*4 + chunk)*2 + ks)*4 + nblk ; lane l elem j:
//   co = nblk*32 + (l&31), ci = chunk*32 + ks*16 + (l>>5)*8 + j
__global__ __launch_bounds__(256) void packw_k(
    const float* w0, const float* w1, const float* w2, const float* w3,
    const float* w4, const float* w5, const float* w6, s16x8* dst) {
  const float* srcs[7] = {w0, w1, w2, w3, w4, w5, w6};
  const int widx = blockIdx.y;
  const float* src = srcs[widx];
  const int gid = blockIdx.x * 256 + threadIdx.x;  // [0,18432)
  const int lane = gid & 63, frag = gid >> 6;      // frag < 288
  const int nblk = frag & 3, ks = (frag >> 2) & 1, chunk = (frag >> 3) & 3, tap = frag >> 5;
  const int co = nblk * 32 + (lane & 31);
  const int cib = chunk * 32 + ks * 16 + (lane >> 5) * 8;
  s16x8 v;
#pragma unroll
  for (int j = 0; j < 8; ++j)
    v[j] = bf16b(src[((size_t)co * 128 + cib + j) * 9 + tap]);
  dst[(size_t)widx * 18432 + (size_t)frag * 64 + lane] = v;
}

// ---------------- NCHW f32 -> NHWC bf16 ----------------
template <int TW>
__global__ __launch_bounds__(256) void nchw2nhwc_k(
    const float* __restrict__ in, uint16_t* __restrict__ out, int H, int W) {
  __shared__ float tile[128][TW + 1];
  const int b = blockIdx.z, h = blockIdx.y, w0 = blockIdx.x * TW;
  for (int idx = threadIdx.x; idx < 128 * TW; idx += 256) {
    int c = idx / TW, w = idx - c * TW;
    tile[c][w] = in[(((size_t)b * 128 + c) * H + h) * W + w0 + w];
  }
  __syncthreads();
  for (int idx = threadIdx.x; idx < TW * 16; idx += 256) {
    int w = idx >> 4, cg = idx & 15;
    s16x8 v;
#pragma unroll
    for (int j = 0; j < 8; ++j) v[j] = bf16b(tile[cg * 8 + j][w]);
    *reinterpret_cast<s16x8*>(out + ((((size_t)b * H + h) * W + w0 + w) << 7) + cg * 8) = v;
  }
}

// ---------------- MFMA conv v8: counted-vmcnt, ONE barrier per chunk ----------------
// Tile: 4 rows x 32 cols x 128 co; 4 waves = co-slices; wave = 128px x 32co.
// Per 32-ci chunk: 3 soft-phases (p = kx), each {12 deduped ds_read_b128 |
// p<2: 2 global_load_lds for chunk+1} -> lgkmcnt(0)+sched_barrier ->
// setprio(1) 24 MFMA setprio(0) -> 6 wf refills. Chunk end: vmcnt(12)
// (retires this chunk's 4 DMAs; 12 younger refills in flight) -> s_barrier.
// Weights wf[2][9] in regs, refilled for chunk+1 after last use.
// OMODE: 0=NHWC, 1=(b,w,h,e), 3=NCHW
template <int OMODE, bool RELU, typename Tout>
__global__ __launch_bounds__(256, 2) void convmf8_k(
    const uint16_t* __restrict__ in, const s16x8* __restrict__ wpk,
    const float* __restrict__ bias, Tout* __restrict__ out,
    const uint16_t* __restrict__ zp, int H, int W) {
  constexpr int CP = 34, RP = 6, RPCP = RP * CP;  // 204
  constexpr int SLOTS = 4 * RPCP;                 // 816
  constexpr int SPT = 4;                          // 1024 padded slots
  __shared__ s16x8 lds[2][SPT * 256];             // 32 KB
  const int b = blockIdx.z, r0 = blockIdx.y * 4, c0 = blockIdx.x * 32;
  const int tid = threadIdx.x, lane = tid & 63, wn = tid >> 6;
  const int wbase = tid & 192;

  // per-slot global source addresses (once)
  const uint16_t* gsrc[SPT];
#pragma unroll
  for (int i = 0; i < SPT; ++i) {
    const int s = tid + i * 256;
    const int kq = s / RPCP;
    const int rem = s - kq * RPCP;
    const int r = rem / CP, c = rem - r * CP;
    const int gr = r0 + r - 1, gc = c0 + c - 1;
    const bool ok = (s < SLOTS) && gr >= 0 && gr < H && gc >= 0 && gc < W;
    gsrc[i] = ok ? (in + (((size_t)b * H + gr) * W + gc) * 128 + kq * 8) : zp;
  }

  // weight base; frag offset for (tap, chunk, ks) = ((tap*4+chunk)*2+ks)*256
  const s16x8* __restrict__ wbl = wpk + wn * 64 + lane;
  s16x8 wf[2][9];
#pragma unroll
  for (int ks = 0; ks < 2; ++ks)
#pragma unroll
    for (int t = 0; t < 9; ++t) wf[ks][t] = wbl[(t * 8 + ks) * 256];  // chunk 0

  // prologue: DMA chunk0 -> buf0; one full drain before the loop
#pragma unroll
  for (int i = 0; i < SPT; ++i) gll16(gsrc[i], &lds[0][wbase + i * 256]);

  f32x16 acc[4];
#pragma unroll
  for (int i = 0; i < 4; ++i)
#pragma unroll
    for (int r = 0; r < 16; ++r) acc[i][r] = 0.f;

  const int abase = (lane >> 5) * RPCP + (lane & 31);
  WAITVM(0);
  __builtin_amdgcn_s_barrier();
  __builtin_amdgcn_sched_barrier(0);

#pragma unroll
  for (int chunk = 0; chunk < 4; ++chunk) {
    const int cb = chunk & 1;
    const s16x8* __restrict__ Lb = &lds[cb][abase];
#pragma unroll
    for (int p = 0; p < 3; ++p) {  // p = kx (soft-phase, no barrier)
      const int kx = p;
      // 12 deduped A row-fragments (both ks) for this kx
      s16x8 ar[2][6];
#pragma unroll
      for (int ks = 0; ks < 2; ++ks)
#pragma unroll
        for (int r = 0; r < 6; ++r) ar[ks][r] = Lb[ks * 2 * RPCP + r * CP + kx];
      // stagger next chunk's DMA: 2 slots in p0, 2 in p1
      if (chunk < 3 && p < 2) {
        gll16(gsrc[2 * p] + (chunk + 1) * 32, &lds[cb ^ 1][wbase + (2 * p) * 256]);
        gll16(gsrc[2 * p + 1] + (chunk + 1) * 32, &lds[cb ^ 1][wbase + (2 * p + 1) * 256]);
      }
      __builtin_amdgcn_sched_barrier(0);
      WAITLGKM0;
      __builtin_amdgcn_sched_barrier(0);
      __builtin_amdgcn_s_setprio(1);
#pragma unroll
      for (int ks = 0; ks < 2; ++ks) {
#pragma unroll
        for (int ky = 0; ky < 3; ++ky) {
#pragma unroll
          for (int mf = 0; mf < 4; ++mf)
            acc[mf] = __builtin_amdgcn_mfma_f32_32x32x16_bf16(ar[ks][mf + ky], wf[ks][ky * 3 + kx],
                                                              acc[mf], 0, 0, 0);
        }
      }
      __builtin_amdgcn_s_setprio(0);
      // refill the 6 just-used wf slots (3 taps x 2 ks) for chunk+1
      if (chunk < 3) {
#pragma unroll
        for (int ks = 0; ks < 2; ++ks)
#pragma unroll
          for (int ky = 0; ky < 3; ++ky) {
            const int tap = ky * 3 + kx;
            wf[ks][tap] = wbl[((tap * 4 + chunk + 1) * 2 + ks) * 256];
          }
      }
      __builtin_amdgcn_sched_barrier(0);
    }
    if (chunk < 3) {
      WAITVM(12);  // retire this chunk's 4 DMAs (12 younger refills stay in flight)
      __builtin_amdgcn_s_barrier();
      __builtin_amdgcn_sched_barrier(0);
    }
  }

  // epilogue: C/D map co=lane&31, px = (reg&3)+8*(reg>>2)+4*(lane>>5)
  const int co = wn * 32 + (lane & 31);
  const float bv = bias[co];
#pragma unroll
  for (int mf = 0; mf < 4; ++mf) {
    const int gr = r0 + mf;
#pragma unroll
    for (int reg = 0; reg < 16; ++reg) {
      const int gc = c0 + (reg & 3) + 8 * (reg >> 2) + 4 * (lane >> 5);
      float v = acc[mf][reg] + bv;
      if (RELU) v = fmaxf(v, 0.f);
      size_t idx;
      if (OMODE == 0)      idx = (((size_t)b * H + gr) * W + gc) * 128 + co;
      else if (OMODE == 1) idx = (((size_t)b * W + gc) * H + gr) * 128 + co;
      else                 idx = (((size_t)b * 128 + co) * H + gr) * W + gc;
      if constexpr (sizeof(Tout) == 2) ((uint16_t*)out)[idx] = (uint16_t)bf16b(v);
      else out[idx] = v;
    }
  }
}

// ---------------- attention: dot + softmax (b128 loads, shuffle reduce) ----------------
__global__ __launch_bounds__(128) void attn_dot_k(
    const float* __restrict__ qg, const uint16_t* __restrict__ Kg,
    const int* __restrict__ u, float* __restrict__ pout) {
  const int bs = blockIdx.x;
  const int b = bs >> 10;
  const int tid = threadIdx.x;  // h
  __shared__ float sq[128];
  __shared__ float wred[2][2];
  sq[tid] = qg[(size_t)bs * 128 + tid];
  int w = u[bs]; w = w < 0 ? 0 : (w > 511 ? 511 : w);
  __syncthreads();
  const s16x8* kp = reinterpret_cast<const s16x8*>(
      Kg + (((size_t)b * 512 + w) * 128 + tid) * 128);
  float acc = 0.f;
#pragma unroll
  for (int i = 0; i < 16; ++i) {
    s16x8 v = kp[i];
#pragma unroll
    for (int j = 0; j < 8; ++j)
      acc = fmaf(sq[i * 8 + j], bfu((uint16_t)v[j]), acc);
  }
  const float d = acc * 0.17677669529663687f;
  float m = d;
#pragma unroll
  for (int o = 1; o < 64; o <<= 1) m = fmaxf(m, __shfl_xor(m, o));
  if ((tid & 63) == 0) wred[0][tid >> 6] = m;
  __syncthreads();
  m = fmaxf(wred[0][0], wred[0][1]);
  const float e = expf(d - m);
  float s = e;
#pragma unroll
  for (int o = 1; o < 64; o <<= 1) s += __shfl_xor(s, o);
  if ((tid & 63) == 0) wred[1][tid >> 6] = s;
  __syncthreads();
  s = wred[1][0] + wred[1][1];
  pout[(size_t)bs * 128 + tid] = e / s;
}

// ---------------- attention: P @ V_gathered -> (b,s,e) bf16 (coalesced b128) ----------------
__global__ __launch_bounds__(128) void attn_pv_k(
    const float* __restrict__ pin, const uint16_t* __restrict__ Vg,
    const int* __restrict__ u, uint16_t* __restrict__ aout) {
  const int bs = blockIdx.x;
  const int b = bs >> 10;
  const int tid = threadIdx.x;
  const int eo = tid & 15, hg = tid >> 4;  // e-octet, h-group
  __shared__ float sp[128];
  __shared__ float red[8][128];
  sp[tid] = pin[(size_t)bs * 128 + tid];
  int w = u[bs]; w = w < 0 ? 0 : (w > 511 ? 511 : w);
  __syncthreads();
  const s16x8* vp = reinterpret_cast<const s16x8*>(
      Vg + ((size_t)b * 512 + w) * 16384) + eo;  // row h at vp[h*16]
  float a8[8];
#pragma unroll
  for (int j = 0; j < 8; ++j) a8[j] = 0.f;
#pragma unroll
  for (int hh = 0; hh < 16; ++hh) {
    const int h = hg * 16 + hh;
    s16x8 v = vp[h * 16];
    const float p = sp[h];
#pragma unroll
    for (int j = 0; j < 8; ++j) a8[j] = fmaf(p, bfu((uint16_t)v[j]), a8[j]);
  }
#pragma unroll
  for (int j = 0; j < 8; ++j) red[hg][eo * 8 + j] = a8[j];
  __syncthreads();
  float r = 0.f;
#pragma unroll
  for (int g = 0; g < 8; ++g) r += red[g][tid];
  aout[(size_t)bs * 128 + tid] = (uint16_t)bf16b(r);
}

// ---------------- launch ----------------
extern "C" void kernel_launch(void* const* d_in, const int* in_sizes, int n_in,
                              void* d_out, int out_size, void* d_ws, size_t ws_size,
                              hipStream_t stream) {
  const float* x      = (const float*)d_in[0];
  const float* y      = (const float*)d_in[1];
  const int*   u      = (const int*)d_in[2];
  const float* q_w1   = (const float*)d_in[3];
  const float* q_b1   = (const float*)d_in[4];
  const float* q_w2   = (const float*)d_in[5];
  const float* q_b2   = (const float*)d_in[6];
  const float* k_w1   = (const float*)d_in[7];
  const float* k_b1   = (const float*)d_in[8];
  const float* k_w2   = (const float*)d_in[9];
  const float* k_b2   = (const float*)d_in[10];
  const float* v_w1   = (const float*)d_in[11];
  const float* v_b1   = (const float*)d_in[12];
  const float* v_w2   = (const float*)d_in[13];
  const float* v_b2   = (const float*)d_in[14];
  const float* proj_w = (const float*)d_in[15];
  const float* proj_b = (const float*)d_in[16];
  float* out = (float*)d_out;

  char* ws = (char*)d_ws;
  const size_t MB = 1 << 20;
  const size_t BIG = 64 * MB;
  const bool tierB = ws_size >= 203 * MB;  // 3 big buffers -> skip 2nd y-transform
  uint16_t* A  = (uint16_t*)ws;            // ybf (NHWC bf16)
  uint16_t* Bb = (uint16_t*)(ws + BIG);    // k1 / v1
  uint16_t* KV = tierB ? (uint16_t*)(ws + 2 * BIG) : A;  // K / V in (b,w,h,e)
  char* sm = ws + (tierB ? 3 : 2) * BIG;
  float*    qg  = (float*)sm;                    // 2 MB
  float*    pb  = (float*)(sm + 2 * MB);         // 2 MB
  uint16_t* xbf = (uint16_t*)(sm + 4 * MB);      // 1 MB
  uint16_t* t1  = (uint16_t*)(sm + 5 * MB);      // 1 MB
  uint16_t* ab  = (uint16_t*)(sm + 6 * MB);      // 1 MB
  s16x8*    wpk = (s16x8*)(sm + 7 * MB);         // ~2.02 MB
  uint16_t* zp  = (uint16_t*)(sm + 10 * MB);     // 1 KB zeros

  hipMemsetAsync(zp, 0, 1024, stream);
  packw_k<<<dim3(72, 7), 256, 0, stream>>>(q_w1, q_w2, k_w1, k_w2, v_w1, v_w2, proj_w, wpk);
  nchw2nhwc_k<32><<<dim3(1, 32, 4), 256, 0, stream>>>(x, xbf, 32, 32);
  nchw2nhwc_k<64><<<dim3(8, 128, 4), 256, 0, stream>>>(y, A, 128, 512);
  // Q path
  convmf8_k<0, true,  uint16_t><<<dim3(1, 8, 4), 256, 0, stream>>>(xbf, wpk + 0 * 18432, q_b1, t1, zp, 32, 32);
  convmf8_k<0, false, float   ><<<dim3(1, 8, 4), 256, 0, stream>>>(t1,  wpk + 1 * 18432, q_b2, qg, zp, 32, 32);
  // K path
  convmf8_k<0, true,  uint16_t><<<dim3(16, 32, 4), 256, 0, stream>>>(A,  wpk + 2 * 18432, k_b1, Bb, zp, 128, 512);
  convmf8_k<1, false, uint16_t><<<dim3(16, 32, 4), 256, 0, stream>>>(Bb, wpk + 3 * 18432, k_b2, KV, zp, 128, 512);
  attn_dot_k<<<dim3(4096), 128, 0, stream>>>(qg, KV, u, pb);
  // V path
  if (!tierB) nchw2nhwc_k<64><<<dim3(8, 128, 4), 256, 0, stream>>>(y, A, 128, 512);
  convmf8_k<0, true,  uint16_t><<<dim3(16, 32, 4), 256, 0, stream>>>(A,  wpk + 4 * 18432, v_b1, Bb, zp, 128, 512);
  convmf8_k<1, false, uint16_t><<<dim3(16, 32, 4), 256, 0, stream>>>(Bb, wpk + 5 * 18432, v_b2, KV, zp, 128, 512);
  attn_pv_k<<<dim3(4096), 128, 0, stream>>>(pb, KV, u, ab);
  // proj
  convmf8_k<3, true, float><<<dim3(1, 8, 4), 256, 0, stream>>>(ab, wpk + 6 * 18432, proj_b, out, zp, 32, 32);
}

// Round 12
// 430.770 us; speedup vs baseline: 1.0370x; 1.0370x over previous
//
#include <hip/hip_runtime.h>
#include <stdint.h>

typedef __attribute__((ext_vector_type(16))) float f32x16;
typedef __attribute__((ext_vector_type(8))) short s16x8;

#define WAITVM(n) asm volatile("s_waitcnt vmcnt(" #n ")" ::: "memory")
#define WAITLGKM0 asm volatile("s_waitcnt lgkmcnt(0)" ::: "memory")

__device__ inline short bf16b(float f) {
  uint32_t x = __float_as_uint(f);
  return (short)((x + 0x7fffu + ((x >> 16) & 1u)) >> 16);  // RNE, finite inputs
}
__device__ inline float bfu(uint16_t u) { return __uint_as_float(((uint32_t)u) << 16); }

__device__ inline void gll16(const void* g, void* l) {
  __builtin_amdgcn_global_load_lds((const __attribute__((address_space(1))) void*)g,
                                   (__attribute__((address_space(3))) void*)l, 16, 0, 0);
}

// ---------------- weight pack: (co,ci,3,3) f32 -> 32x32x16 B-fragment order ----------------
// frag idx = ((tap*4 + chunk)*2 + ks)*4 + nblk ; lane l elem j:
//   co = nblk*32 + (l&31), ci = chunk*32 + ks*16 + (l>>5)*8 + j
__global__ __launch_bounds__(256) void packw_k(
    const float* w0, const float* w1, const float* w2, const float* w3,
    const float* w4, const float* w5, const float* w6, s16x8* dst) {
  const float* srcs[7] = {w0, w1, w2, w3, w4, w5, w6};
  const int widx = blockIdx.y;
  const float* src = srcs[widx];
  const int gid = blockIdx.x * 256 + threadIdx.x;  // [0,18432)
  const int lane = gid & 63, frag = gid >> 6;      // frag < 288
  const int nblk = frag & 3, ks = (frag >> 2) & 1, chunk = (frag >> 3) & 3, tap = frag >> 5;
  const int co = nblk * 32 + (lane & 31);
  const int cib = chunk * 32 + ks * 16 + (lane >> 5) * 8;
  s16x8 v;
#pragma unroll
  for (int j = 0; j < 8; ++j)
    v[j] = bf16b(src[((size_t)co * 128 + cib + j) * 9 + tap]);
  dst[(size_t)widx * 18432 + (size_t)frag * 64 + lane] = v;
}

// ---------------- NCHW f32 -> NHWC bf16 ----------------
template <int TW>
__global__ __launch_bounds__(256) void nchw2nhwc_k(
    const float* __restrict__ in, uint16_t* __restrict__ out, int H, int W) {
  __shared__ float tile[128][TW + 1];
  const int b = blockIdx.z, h = blockIdx.y, w0 = blockIdx.x * TW;
  for (int idx = threadIdx.x; idx < 128 * TW; idx += 256) {
    int c = idx / TW, w = idx - c * TW;
    tile[c][w] = in[(((size_t)b * 128 + c) * H + h) * W + w0 + w];
  }
  __syncthreads();
  for (int idx = threadIdx.x; idx < TW * 16; idx += 256) {
    int w = idx >> 4, cg = idx & 15;
    s16x8 v;
#pragma unroll
    for (int j = 0; j < 8; ++j) v[j] = bf16b(tile[cg * 8 + j][w]);
    *reinterpret_cast<s16x8*>(out + ((((size_t)b * H + h) * W + w0 + w) << 7) + cg * 8) = v;
  }
}

// ---------------- MFMA conv v7: 6-phase schedule (r10 proven best) ----------------
// Tile: 4 rows x 32 cols x 128 co; 4 waves = co-slices; wave = 128px x 32co.
// Per 32-ci chunk: 6 phases (p = ks*3+kx), each:
//   {6 ds_read_b128 | phases 0-3: 1 global_load_lds for chunk+1} -> s_barrier ->
//   lgkmcnt(0)+sched_barrier -> setprio(1) 12 MFMA setprio(0) -> 3 wf refills ->
//   (p==5: counted vmcnt(9) retiring this chunk's 4 DMAs) -> s_barrier.
// No vmcnt(0) drain in the loop; weights live in wf[9] regs.
// OMODE: 0=NHWC, 1=(b,w,h,e), 3=NCHW
template <int OMODE, bool RELU, typename Tout>
__global__ __launch_bounds__(256, 3) void convmf7_k(
    const uint16_t* __restrict__ in, const s16x8* __restrict__ wpk,
    const float* __restrict__ bias, Tout* __restrict__ out,
    const uint16_t* __restrict__ zp, int H, int W) {
  constexpr int CP = 34, RP = 6, RPCP = RP * CP;  // 204
  constexpr int SLOTS = 4 * RPCP;                 // 816
  constexpr int SPT = 4;                          // 1024 padded slots
  __shared__ s16x8 lds[2][SPT * 256];             // 32 KB
  const int b = blockIdx.z, r0 = blockIdx.y * 4, c0 = blockIdx.x * 32;
  const int tid = threadIdx.x, lane = tid & 63, wn = tid >> 6;
  const int wbase = tid & 192;

  // per-slot global source addresses (once)
  const uint16_t* gsrc[SPT];
#pragma unroll
  for (int i = 0; i < SPT; ++i) {
    const int s = tid + i * 256;
    const int kq = s / RPCP;
    const int rem = s - kq * RPCP;
    const int r = rem / CP, c = rem - r * CP;
    const int gr = r0 + r - 1, gc = c0 + c - 1;
    const bool ok = (s < SLOTS) && gr >= 0 && gr < H && gc >= 0 && gc < W;
    gsrc[i] = ok ? (in + (((size_t)b * H + gr) * W + gc) * 128 + kq * 8) : zp;
  }

  // weight base; frag offset for (tap, chunk, ks) = ((tap*4+chunk)*2+ks)*256
  const s16x8* __restrict__ wbl = wpk + wn * 64 + lane;
  s16x8 wf[9];
#pragma unroll
  for (int t = 0; t < 9; ++t) wf[t] = wbl[t * 2048];  // chunk 0, ks 0

  // prologue: DMA chunk0 -> buf0; full drain once; align
#pragma unroll
  for (int i = 0; i < SPT; ++i) gll16(gsrc[i], &lds[0][wbase + i * 256]);

  f32x16 acc[4];
#pragma unroll
  for (int i = 0; i < 4; ++i)
#pragma unroll
    for (int r = 0; r < 16; ++r) acc[i][r] = 0.f;

  const int abase = (lane >> 5) * RPCP + (lane & 31);
  WAITVM(0);
  __builtin_amdgcn_s_barrier();
  __builtin_amdgcn_sched_barrier(0);

#pragma unroll
  for (int chunk = 0; chunk < 4; ++chunk) {
    const int cb = chunk & 1;
    const s16x8* __restrict__ Lb = &lds[cb][abase];
#pragma unroll
    for (int p = 0; p < 6; ++p) {  // p = ks*3 + kx
      const int ks = p / 3, kx = p - ks * 3;
      // 6 deduped A row-fragments for this (ks,kx)
      s16x8 ar[6];
#pragma unroll
      for (int r = 0; r < 6; ++r) ar[r] = Lb[ks * 2 * RPCP + r * CP + kx];
      // stagger next chunk's DMA: one slot per phase, phases 0-3
      if (chunk < 3 && p < SPT)
        gll16(gsrc[p] + (chunk + 1) * 32, &lds[cb ^ 1][wbase + p * 256]);
      __builtin_amdgcn_sched_barrier(0);
      __builtin_amdgcn_s_barrier();
      WAITLGKM0;
      __builtin_amdgcn_sched_barrier(0);
      __builtin_amdgcn_s_setprio(1);
#pragma unroll
      for (int ky = 0; ky < 3; ++ky) {
#pragma unroll
        for (int mf = 0; mf < 4; ++mf)
          acc[mf] = __builtin_amdgcn_mfma_f32_32x32x16_bf16(ar[mf + ky], wf[ky * 3 + kx],
                                                            acc[mf], 0, 0, 0);
      }
      __builtin_amdgcn_s_setprio(0);
      // refill the 3 just-used wf slots with the NEXT phase's frags
      if (!(chunk == 3 && ks == 1)) {
        const int nc = (ks == 0) ? chunk : chunk + 1;
        const int nks = (ks == 0) ? 1 : 0;
#pragma unroll
        for (int ky = 0; ky < 3; ++ky) {
          const int tap = ky * 3 + kx;
          wf[tap] = wbl[((tap * 4 + nc) * 2 + nks) * 256];
        }
      }
      __builtin_amdgcn_sched_barrier(0);
      if (p == 5 && chunk < 3) WAITVM(9);  // retire this chunk's 4 DMAs (9 younger refills in flight)
      __builtin_amdgcn_s_barrier();
    }
  }

  // epilogue: C/D map co=lane&31, px = (reg&3)+8*(reg>>2)+4*(lane>>5)
  const int co = wn * 32 + (lane & 31);
  const float bv = bias[co];
#pragma unroll
  for (int mf = 0; mf < 4; ++mf) {
    const int gr = r0 + mf;
#pragma unroll
    for (int reg = 0; reg < 16; ++reg) {
      const int gc = c0 + (reg & 3) + 8 * (reg >> 2) + 4 * (lane >> 5);
      float v = acc[mf][reg] + bv;
      if (RELU) v = fmaxf(v, 0.f);
      size_t idx;
      if (OMODE == 0)      idx = (((size_t)b * H + gr) * W + gc) * 128 + co;
      else if (OMODE == 1) idx = (((size_t)b * W + gc) * H + gr) * 128 + co;
      else                 idx = (((size_t)b * 128 + co) * H + gr) * W + gc;
      if constexpr (sizeof(Tout) == 2) ((uint16_t*)out)[idx] = (uint16_t)bf16b(v);
      else out[idx] = v;
    }
  }
}

// ---------------- attention: dot + softmax (b128 loads, shuffle reduce) ----------------
__global__ __launch_bounds__(128) void attn_dot_k(
    const float* __restrict__ qg, const uint16_t* __restrict__ Kg,
    const int* __restrict__ u, float* __restrict__ pout) {
  const int bs = blockIdx.x;
  const int b = bs >> 10;
  const int tid = threadIdx.x;  // h
  __shared__ float sq[128];
  __shared__ float wred[2][2];
  sq[tid] = qg[(size_t)bs * 128 + tid];
  int w = u[bs]; w = w < 0 ? 0 : (w > 511 ? 511 : w);
  __syncthreads();
  const s16x8* kp = reinterpret_cast<const s16x8*>(
      Kg + (((size_t)b * 512 + w) * 128 + tid) * 128);
  float acc = 0.f;
#pragma unroll
  for (int i = 0; i < 16; ++i) {
    s16x8 v = kp[i];
#pragma unroll
    for (int j = 0; j < 8; ++j)
      acc = fmaf(sq[i * 8 + j], bfu((uint16_t)v[j]), acc);
  }
  const float d = acc * 0.17677669529663687f;
  float m = d;
#pragma unroll
  for (int o = 1; o < 64; o <<= 1) m = fmaxf(m, __shfl_xor(m, o));
  if ((tid & 63) == 0) wred[0][tid >> 6] = m;
  __syncthreads();
  m = fmaxf(wred[0][0], wred[0][1]);
  const float e = expf(d - m);
  float s = e;
#pragma unroll
  for (int o = 1; o < 64; o <<= 1) s += __shfl_xor(s, o);
  if ((tid & 63) == 0) wred[1][tid >> 6] = s;
  __syncthreads();
  s = wred[1][0] + wred[1][1];
  pout[(size_t)bs * 128 + tid] = e / s;
}

// ---------------- attention: P @ V_gathered -> (b,s,e) bf16 (coalesced b128) ----------------
__global__ __launch_bounds__(128) void attn_pv_k(
    const float* __restrict__ pin, const uint16_t* __restrict__ Vg,
    const int* __restrict__ u, uint16_t* __restrict__ aout) {
  const int bs = blockIdx.x;
  const int b = bs >> 10;
  const int tid = threadIdx.x;
  const int eo = tid & 15, hg = tid >> 4;  // e-octet, h-group
  __shared__ float sp[128];
  __shared__ float red[8][128];
  sp[tid] = pin[(size_t)bs * 128 + tid];
  int w = u[bs]; w = w < 0 ? 0 : (w > 511 ? 511 : w);
  __syncthreads();
  const s16x8* vp = reinterpret_cast<const s16x8*>(
      Vg + ((size_t)b * 512 + w) * 16384) + eo;  // row h at vp[h*16]
  float a8[8];
#pragma unroll
  for (int j = 0; j < 8; ++j) a8[j] = 0.f;
#pragma unroll
  for (int hh = 0; hh < 16; ++hh) {
    const int h = hg * 16 + hh;
    s16x8 v = vp[h * 16];
    const float p = sp[h];
#pragma unroll
    for (int j = 0; j < 8; ++j) a8[j] = fmaf(p, bfu((uint16_t)v[j]), a8[j]);
  }
#pragma unroll
  for (int j = 0; j < 8; ++j) red[hg][eo * 8 + j] = a8[j];
  __syncthreads();
  float r = 0.f;
#pragma unroll
  for (int g = 0; g < 8; ++g) r += red[g][tid];
  aout[(size_t)bs * 128 + tid] = (uint16_t)bf16b(r);
}

// ---------------- launch ----------------
extern "C" void kernel_launch(void* const* d_in, const int* in_sizes, int n_in,
                              void* d_out, int out_size, void* d_ws, size_t ws_size,
                              hipStream_t stream) {
  const float* x      = (const float*)d_in[0];
  const float* y      = (const float*)d_in[1];
  const int*   u      = (const int*)d_in[2];
  const float* q_w1   = (const float*)d_in[3];
  const float* q_b1   = (const float*)d_in[4];
  const float* q_w2   = (const float*)d_in[5];
  const float* q_b2   = (const float*)d_in[6];
  const float* k_w1   = (const float*)d_in[7];
  const float* k_b1   = (const float*)d_in[8];
  const float* k_w2   = (const float*)d_in[9];
  const float* k_b2   = (const float*)d_in[10];
  const float* v_w1   = (const float*)d_in[11];
  const float* v_b1   = (const float*)d_in[12];
  const float* v_w2   = (const float*)d_in[13];
  const float* v_b2   = (const float*)d_in[14];
  const float* proj_w = (const float*)d_in[15];
  const float* proj_b = (const float*)d_in[16];
  float* out = (float*)d_out;

  char* ws = (char*)d_ws;
  const size_t MB = 1 << 20;
  const size_t BIG = 64 * MB;
  const bool tierB = ws_size >= 203 * MB;  // 3 big buffers -> skip 2nd y-transform
  uint16_t* A  = (uint16_t*)ws;            // ybf (NHWC bf16)
  uint16_t* Bb = (uint16_t*)(ws + BIG);    // k1 / v1
  uint16_t* KV = tierB ? (uint16_t*)(ws + 2 * BIG) : A;  // K / V in (b,w,h,e)
  char* sm = ws + (tierB ? 3 : 2) * BIG;
  float*    qg  = (float*)sm;                    // 2 MB
  float*    pb  = (float*)(sm + 2 * MB);         // 2 MB
  uint16_t* xbf = (uint16_t*)(sm + 4 * MB);      // 1 MB
  uint16_t* t1  = (uint16_t*)(sm + 5 * MB);      // 1 MB
  uint16_t* ab  = (uint16_t*)(sm + 6 * MB);      // 1 MB
  s16x8*    wpk = (s16x8*)(sm + 7 * MB);         // ~2.02 MB
  uint16_t* zp  = (uint16_t*)(sm + 10 * MB);     // 1 KB zeros

  hipMemsetAsync(zp, 0, 1024, stream);
  packw_k<<<dim3(72, 7), 256, 0, stream>>>(q_w1, q_w2, k_w1, k_w2, v_w1, v_w2, proj_w, wpk);
  nchw2nhwc_k<32><<<dim3(1, 32, 4), 256, 0, stream>>>(x, xbf, 32, 32);
  nchw2nhwc_k<64><<<dim3(8, 128, 4), 256, 0, stream>>>(y, A, 128, 512);
  // Q path
  convmf7_k<0, true,  uint16_t><<<dim3(1, 8, 4), 256, 0, stream>>>(xbf, wpk + 0 * 18432, q_b1, t1, zp, 32, 32);
  convmf7_k<0, false, float   ><<<dim3(1, 8, 4), 256, 0, stream>>>(t1,  wpk + 1 * 18432, q_b2, qg, zp, 32, 32);
  // K path
  convmf7_k<0, true,  uint16_t><<<dim3(16, 32, 4), 256, 0, stream>>>(A,  wpk + 2 * 18432, k_b1, Bb, zp, 128, 512);
  convmf7_k<1, false, uint16_t><<<dim3(16, 32, 4), 256, 0, stream>>>(Bb, wpk + 3 * 18432, k_b2, KV, zp, 128, 512);
  attn_dot_k<<<dim3(4096), 128, 0, stream>>>(qg, KV, u, pb);
  // V path
  if (!tierB) nchw2nhwc_k<64><<<dim3(8, 128, 4), 256, 0, stream>>>(y, A, 128, 512);
  convmf7_k<0, true,  uint16_t><<<dim3(16, 32, 4), 256, 0, stream>>>(A,  wpk + 4 * 18432, v_b1, Bb, zp, 128, 512);
  convmf7_k<1, false, uint16_t><<<dim3(16, 32, 4), 256, 0, stream>>>(Bb, wpk + 5 * 18432, v_b2, KV, zp, 128, 512);
  attn_pv_k<<<dim3(4096), 128, 0, stream>>>(pb, KV, u, ab);
  // proj
  convmf7_k<3, true, float><<<dim3(1, 8, 4), 256, 0, stream>>>(ab, wpk + 6 * 18432, proj_b, out, zp, 32, 32);
}